// Round 15
// baseline (266.908 us; speedup 1.0000x reference)
//
#include <hip/hip_runtime.h>
#include <hip/hip_bf16.h>

#define DM 1024
#define NH 16
#define HD 64
#define BATCH 2
#define SEQ 2048
#define MROWS (BATCH*SEQ)   // 4096

typedef __attribute__((ext_vector_type(8))) short bf16x8;
typedef __attribute__((ext_vector_type(4))) short bf16x4;
typedef __attribute__((ext_vector_type(4))) float f32x4;
typedef __attribute__((ext_vector_type(4))) unsigned u32x4;

#define LOG2E 1.44269504088896f

__device__ __forceinline__ short f2b(float f) {
  union { float f; unsigned u; } x; x.f = f;
  unsigned r = x.u + 0x7fffu + ((x.u >> 16) & 1u);
  return (short)(r >> 16);
}

__device__ __forceinline__ unsigned cvtpk(float lo, float hi) {
  unsigned r;
  asm("v_cvt_pk_bf16_f32 %0, %1, %2" : "=v"(r) : "v"(lo), "v"(hi));
  return r;
}

__device__ __forceinline__ float nexp2(float x) {
  return __builtin_amdgcn_exp2f(x);
}

// barrier that does NOT drain outstanding global stores/loads (only LDS ops)
__device__ __forceinline__ void lds_barrier() {
  asm volatile("s_waitcnt lgkmcnt(0)" ::: "memory");
  __builtin_amdgcn_s_barrier();
}

__device__ __forceinline__ void gload16(const void* g, void* l) {
  __builtin_amdgcn_global_load_lds((const __attribute__((address_space(1))) unsigned int*)g,
                                   (__attribute__((address_space(3))) unsigned int*)l, 16, 0, 0);
}

// ---------------- fused prep kernel ----------------
__global__ __launch_bounds__(256) void k_prep(
    const float* __restrict__ x,  const float* __restrict__ Wq,
    const float* __restrict__ Wk, const float* __restrict__ Wv,
    const float* __restrict__ Wo, const float* __restrict__ bq,
    const float* __restrict__ bk, const float* __restrict__ bv,
    const float* __restrict__ gate, const float* __restrict__ ent,
    short* __restrict__ xb, short* __restrict__ Wcat,
    short* __restrict__ Wob, float* __restrict__ bcat) {
  __shared__ float entL[4096];
  const int bid = blockIdx.x, t = threadIdx.x;
  if (bid < 2048) {                       // x conversion
    int i = (bid * 256 + t) * 8;
    const float4* s4 = (const float4*)(x + i);
    float4 a = s4[0], b = s4[1];
    bf16x8 o;
    o[0]=f2b(a.x); o[1]=f2b(a.y); o[2]=f2b(a.z); o[3]=f2b(a.w);
    o[4]=f2b(b.x); o[5]=f2b(b.y); o[6]=f2b(b.z); o[7]=f2b(b.w);
    *(bf16x8*)(xb + i) = o;
  } else if (bid < 2560) {                // Wq gated
    int i = ((bid - 2048) * 256 + t) * 8;
    int row = i >> 10;
    float sg = (0.125f * LOG2E) / (1.f + __expf(-gate[row]));
    const float4* s4 = (const float4*)(Wq + i);
    float4 a = s4[0], b = s4[1];
    bf16x8 o;
    o[0]=f2b(a.x*sg); o[1]=f2b(a.y*sg); o[2]=f2b(a.z*sg); o[3]=f2b(a.w*sg);
    o[4]=f2b(b.x*sg); o[5]=f2b(b.y*sg); o[6]=f2b(b.z*sg); o[7]=f2b(b.w*sg);
    *(bf16x8*)(Wcat + i) = o;
  } else if (bid < 2624) {                // k_went: Wcat[1024 + h*64+e][c]
    int q = bid - 2560;
    int h = q >> 2, cc = q & 3;
    int c = cc * 256 + t;
#pragma unroll
    for (int j = 0; j < 16; ++j) entL[t + j*256] = ent[h*4096 + t + j*256];
    __syncthreads();
#pragma unroll 1
    for (int ec = 0; ec < 4; ++ec) {
      float acc[16];
#pragma unroll
      for (int e = 0; e < 16; ++e) acc[e] = 0.f;
#pragma unroll 4
      for (int d = 0; d < 64; ++d) {
        float wk = Wk[(size_t)(h*64 + d)*DM + c];
#pragma unroll
        for (int e = 0; e < 16; ++e) acc[e] += entL[d*64 + ec*16 + e] * wk;
      }
#pragma unroll
      for (int e = 0; e < 16; ++e)
        Wcat[(size_t)(1024 + h*64 + ec*16 + e)*DM + c] = f2b(acc[e]);
    }
  } else if (bid < 3136) {                // Wv
    int i = ((bid - 2624) * 256 + t) * 8;
    const float4* s4 = (const float4*)(Wv + i);
    float4 a = s4[0], b = s4[1];
    bf16x8 o;
    o[0]=f2b(a.x); o[1]=f2b(a.y); o[2]=f2b(a.z); o[3]=f2b(a.w);
    o[4]=f2b(b.x); o[5]=f2b(b.y); o[6]=f2b(b.z); o[7]=f2b(b.w);
    *(bf16x8*)(Wcat + (size_t)2048*DM + i) = o;
  } else if (bid < 3648) {                // Wo
    int i = ((bid - 3136) * 256 + t) * 8;
    const float4* s4 = (const float4*)(Wo + i);
    float4 a = s4[0], b = s4[1];
    bf16x8 o;
    o[0]=f2b(a.x); o[1]=f2b(a.y); o[2]=f2b(a.z); o[3]=f2b(a.w);
    o[4]=f2b(b.x); o[5]=f2b(b.y); o[6]=f2b(b.z); o[7]=f2b(b.w);
    *(bf16x8*)(Wob + i) = o;
  } else {                                // bias
    int i = (bid - 3648) * 256 + t;
    float v;
    if (i < 1024) {
      v = bq[i] * ((0.125f * LOG2E) / (1.f + __expf(-gate[i])));
    } else if (i < 2048) {
      int rr = i - 1024, h = rr >> 6, e = rr & 63;
      float a = 0.f;
      for (int d = 0; d < 64; ++d) a += bk[h*64 + d] * ent[h*4096 + d*64 + e];
      v = a;
    } else {
      v = bv[i - 2048];
    }
    bcat[i] = v;
  }
}

// ---------------- GEMM: C[m,n] = sum_k A[m,k]*B[n,k] + bias[n] ----------------

template<int MODE, int LGX>
__global__ __launch_bounds__(256) void gemm_bt(const short* __restrict__ A,
                                               const short* __restrict__ B,
                                               const float* __restrict__ bias,
                                               void* __restrict__ C,
                                               short* __restrict__ vt,
                                               int M, int N, int K) {
  __shared__ __align__(16) short As[128*64];
  __shared__ __align__(16) short Bs[128*64];
  const int t = threadIdx.x, l = t & 63, w = t >> 6;
  const int wr = w >> 1, wc = w & 1;
  const int lin = blockIdx.x + (blockIdx.y << LGX);
  const int nwg = gridDim.x * gridDim.y;
  const int virt = (lin & 7) * (nwg >> 3) + (lin >> 3);
  const int bm = virt & ((1 << LGX) - 1), bn = virt >> LGX;
  const int row_l = l & 15, kg = l >> 4;
  f32x4 acc[4][4];
  {
    f32x4 z = {0.f, 0.f, 0.f, 0.f};
#pragma unroll
    for (int m = 0; m < 4; ++m)
#pragma unroll
      for (int n = 0; n < 4; ++n) acc[m][n] = z;
  }
  for (int k0 = 0; k0 < K; k0 += 64) {
#pragma unroll
    for (int i = 0; i < 4; ++i) {
      int idx = i * 256 + t;
      int row = idx >> 3, cb = (idx & 7) * 8;
      gload16(A + (size_t)(bm*128 + row)*K + k0 + cb, &As[idx*8]);
      gload16(B + (size_t)(bn*128 + row)*K + k0 + cb, &Bs[idx*8]);
    }
    __syncthreads();
#pragma unroll
    for (int ks = 0; ks < 2; ++ks) {
      bf16x8 af[4], bfv[4];
#pragma unroll
      for (int m = 0; m < 4; ++m)
        af[m] = *(const bf16x8*)&As[(wr*64 + m*16 + row_l)*64 + ks*32 + kg*8];
#pragma unroll
      for (int n = 0; n < 4; ++n)
        bfv[n] = *(const bf16x8*)&Bs[(wc*64 + n*16 + row_l)*64 + ks*32 + kg*8];
#pragma unroll
      for (int m = 0; m < 4; ++m)
#pragma unroll
        for (int n = 0; n < 4; ++n)
          acc[m][n] = __builtin_amdgcn_mfma_f32_16x16x32_bf16(af[m], bfv[n], acc[m][n], 0, 0, 0);
    }
    __syncthreads();
  }
  const int r0 = bm*128 + wr*64, c0 = bn*128 + wc*64;
  if (MODE == 1 && c0 >= 2048) {
    const int bb = (bm*128) >> 11;
#pragma unroll
    for (int n = 0; n < 4; ++n) {
      int cv = c0 + n*16 + row_l - 2048;
      int hh = cv >> 6, dd = cv & 63;
      float bvs = bias[c0 + n*16 + row_l];
      short* vrow = vt + ((size_t)((bb*16 + hh)*64 + dd))*SEQ;
#pragma unroll
      for (int m = 0; m < 4; ++m) {
        int s0 = (r0 + m*16 + kg*4) & (SEQ-1);
        bf16x4 o;
        o[0]=f2b(acc[m][n][0]+bvs); o[1]=f2b(acc[m][n][1]+bvs);
        o[2]=f2b(acc[m][n][2]+bvs); o[3]=f2b(acc[m][n][3]+bvs);
        *(bf16x4*)&vrow[s0] = o;
      }
    }
  } else {
#pragma unroll
    for (int n = 0; n < 4; ++n) {
      int col = c0 + n*16 + row_l;
      float bvs = bias[col];
#pragma unroll
      for (int m = 0; m < 4; ++m) {
#pragma unroll
        for (int r = 0; r < 4; ++r) {
          int row = r0 + m*16 + kg*4 + r;
          float v = acc[m][n][r] + bvs;
          if (MODE == 1) ((short*)C)[(size_t)row*2048 + col] = f2b(v);
          else           ((float*)C)[(size_t)row*N + col] = v;
        }
      }
    }
  }
}

// ---- gemm2 variant: 64x128 tile, fp32 out ----
__global__ __launch_bounds__(256) void gemm_bt_small(const short* __restrict__ A,
                                                     const short* __restrict__ B,
                                                     const float* __restrict__ bias,
                                                     float* __restrict__ C,
                                                     int M, int N, int K) {
  __shared__ __align__(16) short As[64*64];
  __shared__ __align__(16) short Bs[128*64];
  const int t = threadIdx.x, l = t & 63, w = t >> 6;
  const int wr = w >> 1, wc = w & 1;
  const int lin = blockIdx.x + (blockIdx.y << 6);
  const int nwg = gridDim.x * gridDim.y;
  const int virt = (lin & 7) * (nwg >> 3) + (lin >> 3);
  const int bm = virt & 63, bn = virt >> 6;
  const int row_l = l & 15, kg = l >> 4;
  f32x4 acc[2][4];
  {
    f32x4 z = {0.f, 0.f, 0.f, 0.f};
#pragma unroll
    for (int m = 0; m < 2; ++m)
#pragma unroll
      for (int n = 0; n < 4; ++n) acc[m][n] = z;
  }
  for (int k0 = 0; k0 < K; k0 += 64) {
#pragma unroll
    for (int i = 0; i < 2; ++i) {
      int idx = i * 256 + t;
      int row = idx >> 3, cb = (idx & 7) * 8;
      gload16(A + (size_t)(bm*64 + row)*K + k0 + cb, &As[idx*8]);
    }
#pragma unroll
    for (int i = 0; i < 4; ++i) {
      int idx = i * 256 + t;
      int row = idx >> 3, cb = (idx & 7) * 8;
      gload16(B + (size_t)(bn*128 + row)*K + k0 + cb, &Bs[idx*8]);
    }
    __syncthreads();
#pragma unroll
    for (int ks = 0; ks < 2; ++ks) {
      bf16x8 af[2], bfv[4];
#pragma unroll
      for (int m = 0; m < 2; ++m)
        af[m] = *(const bf16x8*)&As[(wr*32 + m*16 + row_l)*64 + ks*32 + kg*8];
#pragma unroll
      for (int n = 0; n < 4; ++n)
        bfv[n] = *(const bf16x8*)&Bs[(wc*64 + n*16 + row_l)*64 + ks*32 + kg*8];
#pragma unroll
      for (int m = 0; m < 2; ++m)
#pragma unroll
        for (int n = 0; n < 4; ++n)
          acc[m][n] = __builtin_amdgcn_mfma_f32_16x16x32_bf16(af[m], bfv[n], acc[m][n], 0, 0, 0);
    }
    __syncthreads();
  }
  const int r0 = bm*64 + wr*32, c0 = bn*128 + wc*64;
#pragma unroll
  for (int n = 0; n < 4; ++n) {
    int col = c0 + n*16 + row_l;
    float bvs = bias[col];
#pragma unroll
    for (int m = 0; m < 2; ++m) {
#pragma unroll
      for (int r = 0; r < 4; ++r) {
        int row = r0 + m*16 + kg*4 + r;
        C[(size_t)row*N + col] = acc[m][n][r] + bvs;
      }
    }
  }
}

// ---------------- fused attention (128 q-rows, 8 waves, KVBLK=128) ----------------
// qk: (4096 x 2048) bf16: Q at col h*64, K' at 1024+h*64 (Q pre-scaled by 0.125*log2e).
// vtg: [bh][d][s] bf16 (pre-transposed V).
// KVBLK=128: each phase = two r12 tile-bodies under ONE staging step and ONE
// barrier (16 barriers/pass instead of 32). Pass-2 inner loop split in two
// half-sweeps so pf[4] register pressure is unchanged. Depth-1 reg prefetch
// (window = one double-length phase). K rows g()-permuted per 64-group ->
// verified r5 S^T/PV mapping. XOR-swizzled LDS (2-way conflicts, free).

__global__ __launch_bounds__(512) void attn_fused(const short* __restrict__ qk,
                                                  const short* __restrict__ vtg,
                                                  float* __restrict__ attn_out,
                                                  short* __restrict__ ctx) {
  __shared__ __align__(16) short Ks[2][128*64];   // [key][d]  stride 64
  __shared__ __align__(16) short Vt[2][64*128];   // [d][key]  stride 128
  const int t = threadIdx.x, l = t & 63, w = t >> 6;
  const int row_l = l & 15, kg = l >> 4;
  const int rsl = row_l & 7;
  const int blk = blockIdx.x;
  const int bh = blk >> 4, q0 = (blk & 15) * 128;
  const int b = bh >> 4, h = bh & 15;
  const short* Qp = qk + (size_t)b*SEQ*2048 + h*64;
  const short* Kp = qk + (size_t)b*SEQ*2048 + 1024 + h*64;
  const short* Vg = vtg + (size_t)bh*64*SEQ;
  float* attn_bh = attn_out + (size_t)bh*SEQ*SEQ;
  const int qw = q0 + w*16;

  const bf16x8 aq0 = *(const bf16x8*)(Qp + (size_t)(qw + row_l)*2048 + kg*8);
  const bf16x8 aq1 = *(const bf16x8*)(Qp + (size_t)(qw + row_l)*2048 + 32 + kg*8);

  // staging slots: thread covers K rows a0 and a0+64 (g()-permuted within group),
  // V rows a0 with key-chunks c8 and c8+64 (natural order)
  const int a0 = t >> 3;                 // 0..63
  const int c8 = (t & 7) * 8;
  const int g0 = (a0 & 0x23) | ((a0 & 0x0C) << 1) | ((a0 & 0x10) >> 2);
  const size_t kOff0 = (size_t)g0*2048 + c8;          // key-group 0
  const size_t kOff1 = (size_t)(64 + g0)*2048 + c8;   // key-group 1
  const int wofK0 = a0*64 + (c8 ^ ((a0 & 7) << 3));
  const int wofK1 = wofK0 + 64*64;
  const size_t vOff0 = (size_t)a0*SEQ + c8;           // keys c8..c8+7
  const int wofV0 = a0*128 + (c8 ^ ((a0 & 7) << 3));
  const int wofV1 = wofV0 + 64;                       // keys c8+64..

  // ---- pass 1: rsum; 16 phases of 128 keys, depth-1 prefetch ----
  float rsum = 0.f;
  {
    bf16x8 r0 = *(const bf16x8*)(Kp + kOff0);
    bf16x8 r1 = *(const bf16x8*)(Kp + kOff1);
    *(bf16x8*)&Ks[0][wofK0] = r0;
    *(bf16x8*)&Ks[0][wofK1] = r1;
  }
  lds_barrier();
#pragma unroll 1
  for (int kt = 0; kt < 16; ++kt) {
    const int cur = kt & 1;
    bf16x8 rk0, rk1;
    if (kt < 15) {
      const short* kb = Kp + (size_t)(kt + 1)*128*2048;
      rk0 = *(const bf16x8*)(kb + kOff0);
      rk1 = *(const bf16x8*)(kb + kOff1);
    }
    __builtin_amdgcn_s_setprio(1);
#pragma unroll
    for (int nt = 0; nt < 8; ++nt) {
      const int row = nt*16 + row_l;
      bf16x8 k0 = *(const bf16x8*)&Ks[cur][row*64 + ((kg ^ rsl) << 3)];
      bf16x8 k1 = *(const bf16x8*)&Ks[cur][row*64 + (((kg|4) ^ rsl) << 3)];
      f32x4 s = {0.f, 0.f, 0.f, 0.f};
      s = __builtin_amdgcn_mfma_f32_16x16x32_bf16(k0, aq0, s, 0, 0, 0);
      s = __builtin_amdgcn_mfma_f32_16x16x32_bf16(k1, aq1, s, 0, 0, 0);
      rsum += (nexp2(s[0]) + nexp2(s[1])) + (nexp2(s[2]) + nexp2(s[3]));
    }
    __builtin_amdgcn_s_setprio(0);
    if (kt < 15) {
      *(bf16x8*)&Ks[cur^1][wofK0] = rk0;
      *(bf16x8*)&Ks[cur^1][wofK1] = rk1;
    }
    lds_barrier();
  }
  rsum += __shfl_xor(rsum, 16);
  rsum += __shfl_xor(rsum, 32);
  const float inv = 1.f / rsum;

  f32x4 actx[4];
  {
    f32x4 z = {0.f, 0.f, 0.f, 0.f};
#pragma unroll
    for (int e = 0; e < 4; ++e) actx[e] = z;
  }

  // ---- pass 2: 16 phases of 128 keys; two half-sweeps per phase ----
  {
    bf16x8 r0 = *(const bf16x8*)(Kp + kOff0);
    bf16x8 r1 = *(const bf16x8*)(Kp + kOff1);
    bf16x8 v0 = *(const bf16x8*)(Vg + vOff0);
    bf16x8 v1 = *(const bf16x8*)(Vg + vOff0 + 64);
    *(bf16x8*)&Ks[0][wofK0] = r0;
    *(bf16x8*)&Ks[0][wofK1] = r1;
    *(bf16x8*)&Vt[0][wofV0] = v0;
    *(bf16x8*)&Vt[0][wofV1] = v1;
  }
  lds_barrier();
#pragma unroll 1
  for (int kt = 0; kt < 16; ++kt) {
    const int cur = kt & 1;
    bf16x8 rk0, rk1, rv0, rv1;
    if (kt < 15) {
      const short* kb = Kp + (size_t)(kt + 1)*128*2048;
      const short* vb = Vg + (kt + 1)*128;
      rk0 = *(const bf16x8*)(kb + kOff0);
      rk1 = *(const bf16x8*)(kb + kOff1);
      rv0 = *(const bf16x8*)(vb + vOff0);
      rv1 = *(const bf16x8*)(vb + vOff0 + 64);
    }
    __builtin_amdgcn_s_setprio(1);
#pragma unroll
    for (int half = 0; half < 2; ++half) {
      f32x4 pf[4];
#pragma unroll
      for (int ntl = 0; ntl < 4; ++ntl) {
        const int row = half*64 + ntl*16 + row_l;
        bf16x8 k0 = *(const bf16x8*)&Ks[cur][row*64 + ((kg ^ rsl) << 3)];
        bf16x8 k1 = *(const bf16x8*)&Ks[cur][row*64 + (((kg|4) ^ rsl) << 3)];
        f32x4 s = {0.f, 0.f, 0.f, 0.f};
        s = __builtin_amdgcn_mfma_f32_16x16x32_bf16(k0, aq0, s, 0, 0, 0);
        s = __builtin_amdgcn_mfma_f32_16x16x32_bf16(k1, aq1, s, 0, 0, 0);
        f32x4 p;
        p[0] = nexp2(s[0]) * inv; p[1] = nexp2(s[1]) * inv;
        p[2] = nexp2(s[2]) * inv; p[3] = nexp2(s[3]) * inv;
        *(f32x4*)&attn_bh[(size_t)(qw + row_l)*SEQ + kt*128 + half*64
                          + (ntl&2)*16 + kg*8 + (ntl&1)*4] = p;
        pf[ntl] = p;
      }
#pragma unroll
      for (int hh2 = 0; hh2 < 2; ++hh2) {
        u32x4 pq;
        pq[0] = cvtpk(pf[2*hh2][0],   pf[2*hh2][1]);
        pq[1] = cvtpk(pf[2*hh2][2],   pf[2*hh2][3]);
        pq[2] = cvtpk(pf[2*hh2+1][0], pf[2*hh2+1][1]);
        pq[3] = cvtpk(pf[2*hh2+1][2], pf[2*hh2+1][3]);
        bf16x8 pb = *(bf16x8*)&pq;
        // V col slot (4-bit): ((half<<3)|(hh2<<2)|kg) ^ rsl  (XOR hits low 3 bits)
        const int vslot = ((half << 3) | (hh2 << 2) | kg) ^ rsl;
#pragma unroll
        for (int e = 0; e < 4; ++e) {
          bf16x8 va = *(const bf16x8*)&Vt[cur][(e*16 + row_l)*128 + (vslot << 3)];
          actx[e] = __builtin_amdgcn_mfma_f32_16x16x32_bf16(va, pb, actx[e], 0, 0, 0);
        }
      }
    }
    __builtin_amdgcn_s_setprio(0);
    if (kt < 15) {
      *(bf16x8*)&Ks[cur^1][wofK0] = rk0;
      *(bf16x8*)&Ks[cur^1][wofK1] = rk1;
      *(bf16x8*)&Vt[cur^1][wofV0] = rv0;
      *(bf16x8*)&Vt[cur^1][wofV1] = rv1;
    }
    lds_barrier();
  }
  // ctx epilogue: actx[e] = ctx^T: row d = e*16+kg*4+r, col q = row_l
#pragma unroll
  for (int e = 0; e < 4; ++e) {
    int2 o;
    o.x = (int)cvtpk(actx[e][0], actx[e][1]);
    o.y = (int)cvtpk(actx[e][2], actx[e][3]);
    *(int2*)&ctx[(size_t)(b*SEQ + qw + row_l)*DM + h*64 + e*16 + kg*4] = o;
  }
}

// ---------------- launch ----------------

extern "C" void kernel_launch(void* const* d_in, const int* in_sizes, int n_in,
                              void* d_out, int out_size, void* d_ws, size_t ws_size,
                              hipStream_t stream) {
  const float* x    = (const float*)d_in[0];
  const float* Wq   = (const float*)d_in[1];
  const float* bq   = (const float*)d_in[2];
  const float* Wk   = (const float*)d_in[3];
  const float* bk   = (const float*)d_in[4];
  const float* Wv   = (const float*)d_in[5];
  const float* bv   = (const float*)d_in[6];
  const float* Wo   = (const float*)d_in[7];
  const float* bo   = (const float*)d_in[8];
  const float* gate = (const float*)d_in[9];
  const float* ent  = (const float*)d_in[10];

  char* ws = (char*)d_ws;
  short* xb   = (short*)(ws);                          // 4096x1024 bf16 (8 MB); reused as ctx
  short* Wcat = (short*)(ws + ((size_t)8  << 20));     // 3072x1024 bf16 (6 MB)
  short* Wob  = (short*)(ws + ((size_t)14 << 20));     // 1024x1024 bf16 (2 MB)
  float* bcat = (float*)(ws + ((size_t)16 << 20));     // 3072 f32
  short* qkb  = (short*)(ws + ((size_t)17 << 20));     // 4096x2048 bf16 (16 MB)
  short* vtg  = (short*)(ws + ((size_t)33 << 20));     // 32x64x2048 bf16 (16 MB)
  short* ctxb = xb;                                    // reuse (x consumed by gemm1)

  float* outp  = (float*)d_out;
  float* attnp = outp + (size_t)MROWS * DM;

  k_prep<<<3660, 256, 0, stream>>>(x, Wq, Wk, Wv, Wo, bq, bk, bv, gate, ent,
                                   xb, Wcat, Wob, bcat);
  gemm_bt<1, 5><<<dim3(32, 24), 256, 0, stream>>>(xb, Wcat, bcat, qkb, vtg, MROWS, 3072, DM);
  attn_fused<<<512, 512, 0, stream>>>(qkb, vtg, attnp, ctxb);
  gemm_bt_small<<<dim3(64, 8), 256, 0, stream>>>(ctxb, Wob, bo, outp, MROWS, DM, DM);
}

// Round 16
// 261.048 us; speedup vs baseline: 1.0224x; 1.0224x over previous
//
#include <hip/hip_runtime.h>
#include <hip/hip_bf16.h>

#define DM 1024
#define NH 16
#define HD 64
#define BATCH 2
#define SEQ 2048
#define MROWS (BATCH*SEQ)   // 4096

typedef __attribute__((ext_vector_type(8))) short bf16x8;
typedef __attribute__((ext_vector_type(4))) short bf16x4;
typedef __attribute__((ext_vector_type(4))) float f32x4;
typedef __attribute__((ext_vector_type(4))) unsigned u32x4;

#define LOG2E 1.44269504088896f

__device__ __forceinline__ short f2b(float f) {
  union { float f; unsigned u; } x; x.f = f;
  unsigned r = x.u + 0x7fffu + ((x.u >> 16) & 1u);
  return (short)(r >> 16);
}

__device__ __forceinline__ unsigned cvtpk(float lo, float hi) {
  unsigned r;
  asm("v_cvt_pk_bf16_f32 %0, %1, %2" : "=v"(r) : "v"(lo), "v"(hi));
  return r;
}

__device__ __forceinline__ float nexp2(float x) {
  return __builtin_amdgcn_exp2f(x);
}

// barrier that does NOT drain outstanding global stores/loads (only LDS ops)
__device__ __forceinline__ void lds_barrier() {
  asm volatile("s_waitcnt lgkmcnt(0)" ::: "memory");
  __builtin_amdgcn_s_barrier();
}

__device__ __forceinline__ void gload16(const void* g, void* l) {
  __builtin_amdgcn_global_load_lds((const __attribute__((address_space(1))) unsigned int*)g,
                                   (__attribute__((address_space(3))) unsigned int*)l, 16, 0, 0);
}

// ---------------- fused prep kernel ----------------
__global__ __launch_bounds__(256) void k_prep(
    const float* __restrict__ x,  const float* __restrict__ Wq,
    const float* __restrict__ Wk, const float* __restrict__ Wv,
    const float* __restrict__ Wo, const float* __restrict__ bq,
    const float* __restrict__ bk, const float* __restrict__ bv,
    const float* __restrict__ gate, const float* __restrict__ ent,
    short* __restrict__ xb, short* __restrict__ Wcat,
    short* __restrict__ Wob, float* __restrict__ bcat) {
  __shared__ float entL[4096];
  const int bid = blockIdx.x, t = threadIdx.x;
  if (bid < 2048) {                       // x conversion
    int i = (bid * 256 + t) * 8;
    const float4* s4 = (const float4*)(x + i);
    float4 a = s4[0], b = s4[1];
    bf16x8 o;
    o[0]=f2b(a.x); o[1]=f2b(a.y); o[2]=f2b(a.z); o[3]=f2b(a.w);
    o[4]=f2b(b.x); o[5]=f2b(b.y); o[6]=f2b(b.z); o[7]=f2b(b.w);
    *(bf16x8*)(xb + i) = o;
  } else if (bid < 2560) {                // Wq gated
    int i = ((bid - 2048) * 256 + t) * 8;
    int row = i >> 10;
    float sg = (0.125f * LOG2E) / (1.f + __expf(-gate[row]));
    const float4* s4 = (const float4*)(Wq + i);
    float4 a = s4[0], b = s4[1];
    bf16x8 o;
    o[0]=f2b(a.x*sg); o[1]=f2b(a.y*sg); o[2]=f2b(a.z*sg); o[3]=f2b(a.w*sg);
    o[4]=f2b(b.x*sg); o[5]=f2b(b.y*sg); o[6]=f2b(b.z*sg); o[7]=f2b(b.w*sg);
    *(bf16x8*)(Wcat + i) = o;
  } else if (bid < 2624) {                // k_went: Wcat[1024 + h*64+e][c]
    int q = bid - 2560;
    int h = q >> 2, cc = q & 3;
    int c = cc * 256 + t;
#pragma unroll
    for (int j = 0; j < 16; ++j) entL[t + j*256] = ent[h*4096 + t + j*256];
    __syncthreads();
#pragma unroll 1
    for (int ec = 0; ec < 4; ++ec) {
      float acc[16];
#pragma unroll
      for (int e = 0; e < 16; ++e) acc[e] = 0.f;
#pragma unroll 4
      for (int d = 0; d < 64; ++d) {
        float wk = Wk[(size_t)(h*64 + d)*DM + c];
#pragma unroll
        for (int e = 0; e < 16; ++e) acc[e] += entL[d*64 + ec*16 + e] * wk;
      }
#pragma unroll
      for (int e = 0; e < 16; ++e)
        Wcat[(size_t)(1024 + h*64 + ec*16 + e)*DM + c] = f2b(acc[e]);
    }
  } else if (bid < 3136) {                // Wv
    int i = ((bid - 2624) * 256 + t) * 8;
    const float4* s4 = (const float4*)(Wv + i);
    float4 a = s4[0], b = s4[1];
    bf16x8 o;
    o[0]=f2b(a.x); o[1]=f2b(a.y); o[2]=f2b(a.z); o[3]=f2b(a.w);
    o[4]=f2b(b.x); o[5]=f2b(b.y); o[6]=f2b(b.z); o[7]=f2b(b.w);
    *(bf16x8*)(Wcat + (size_t)2048*DM + i) = o;
  } else if (bid < 3648) {                // Wo
    int i = ((bid - 3136) * 256 + t) * 8;
    const float4* s4 = (const float4*)(Wo + i);
    float4 a = s4[0], b = s4[1];
    bf16x8 o;
    o[0]=f2b(a.x); o[1]=f2b(a.y); o[2]=f2b(a.z); o[3]=f2b(a.w);
    o[4]=f2b(b.x); o[5]=f2b(b.y); o[6]=f2b(b.z); o[7]=f2b(b.w);
    *(bf16x8*)(Wob + i) = o;
  } else {                                // bias
    int i = (bid - 3648) * 256 + t;
    float v;
    if (i < 1024) {
      v = bq[i] * ((0.125f * LOG2E) / (1.f + __expf(-gate[i])));
    } else if (i < 2048) {
      int rr = i - 1024, h = rr >> 6, e = rr & 63;
      float a = 0.f;
      for (int d = 0; d < 64; ++d) a += bk[h*64 + d] * ent[h*4096 + d*64 + e];
      v = a;
    } else {
      v = bv[i - 2048];
    }
    bcat[i] = v;
  }
}

// ---------------- GEMM: C[m,n] = sum_k A[m,k]*B[n,k] + bias[n] ----------------
// MODE 1 only. QK-region blocks (c0<2048) use SWAPPED operand order
// (mfma(bfv,af)) so each lane holds 4 consecutive C-columns -> vectorized
// int2 epilogue (16 stores, 2 cvtpk each) instead of 64 scalar 2B stores.
// V-region blocks (c0>=2048) keep original order (their transposed vt write
// needs row-contiguity). Branch is block-uniform -> barriers stay legal.

template<int MODE, int LGX>
__global__ __launch_bounds__(256) void gemm_bt(const short* __restrict__ A,
                                               const short* __restrict__ B,
                                               const float* __restrict__ bias,
                                               void* __restrict__ C,
                                               short* __restrict__ vt,
                                               int M, int N, int K) {
  __shared__ __align__(16) short As[128*64];
  __shared__ __align__(16) short Bs[128*64];
  const int t = threadIdx.x, l = t & 63, w = t >> 6;
  const int wr = w >> 1, wc = w & 1;
  const int lin = blockIdx.x + (blockIdx.y << LGX);
  const int nwg = gridDim.x * gridDim.y;
  const int virt = (lin & 7) * (nwg >> 3) + (lin >> 3);
  const int bm = virt & ((1 << LGX) - 1), bn = virt >> LGX;
  const int row_l = l & 15, kg = l >> 4;
  const int c0 = bn*128 + wc*64;
  const bool swp = (MODE != 1) || (c0 < 2048);
  f32x4 acc[4][4];
  {
    f32x4 z = {0.f, 0.f, 0.f, 0.f};
#pragma unroll
    for (int m = 0; m < 4; ++m)
#pragma unroll
      for (int n = 0; n < 4; ++n) acc[m][n] = z;
  }
  for (int k0 = 0; k0 < K; k0 += 64) {
#pragma unroll
    for (int i = 0; i < 4; ++i) {
      int idx = i * 256 + t;
      int row = idx >> 3, cb = (idx & 7) * 8;
      gload16(A + (size_t)(bm*128 + row)*K + k0 + cb, &As[idx*8]);
      gload16(B + (size_t)(bn*128 + row)*K + k0 + cb, &Bs[idx*8]);
    }
    __syncthreads();
    if (swp) {
#pragma unroll
      for (int ks = 0; ks < 2; ++ks) {
        bf16x8 af[4], bfv[4];
#pragma unroll
        for (int m = 0; m < 4; ++m)
          af[m] = *(const bf16x8*)&As[(wr*64 + m*16 + row_l)*64 + ks*32 + kg*8];
#pragma unroll
        for (int n = 0; n < 4; ++n)
          bfv[n] = *(const bf16x8*)&Bs[(wc*64 + n*16 + row_l)*64 + ks*32 + kg*8];
#pragma unroll
        for (int m = 0; m < 4; ++m)
#pragma unroll
          for (int n = 0; n < 4; ++n)
            acc[m][n] = __builtin_amdgcn_mfma_f32_16x16x32_bf16(bfv[n], af[m], acc[m][n], 0, 0, 0);
      }
    } else {
#pragma unroll
      for (int ks = 0; ks < 2; ++ks) {
        bf16x8 af[4], bfv[4];
#pragma unroll
        for (int m = 0; m < 4; ++m)
          af[m] = *(const bf16x8*)&As[(wr*64 + m*16 + row_l)*64 + ks*32 + kg*8];
#pragma unroll
        for (int n = 0; n < 4; ++n)
          bfv[n] = *(const bf16x8*)&Bs[(wc*64 + n*16 + row_l)*64 + ks*32 + kg*8];
#pragma unroll
        for (int m = 0; m < 4; ++m)
#pragma unroll
          for (int n = 0; n < 4; ++n)
            acc[m][n] = __builtin_amdgcn_mfma_f32_16x16x32_bf16(af[m], bfv[n], acc[m][n], 0, 0, 0);
      }
    }
    __syncthreads();
  }
  const int r0 = bm*128 + wr*64;
  if (MODE == 1 && c0 < 2048) {
    // swapped fragment: row = r0+m*16+row_l, cols c0+n*16+kg*4 .. +3
#pragma unroll
    for (int m = 0; m < 4; ++m) {
      int row = r0 + m*16 + row_l;
      short* crow = (short*)C + (size_t)row*2048;
#pragma unroll
      for (int n = 0; n < 4; ++n) {
        int colb = c0 + n*16 + kg*4;
        f32x4 bv4 = *(const f32x4*)&bias[colb];
        int2 o;
        o.x = (int)cvtpk(acc[m][n][0] + bv4[0], acc[m][n][1] + bv4[1]);
        o.y = (int)cvtpk(acc[m][n][2] + bv4[2], acc[m][n][3] + bv4[3]);
        *(int2*)&crow[colb] = o;
      }
    }
  } else if (MODE == 1) {
    // original fragment: V written transposed vt[(b*16+h)*64 + d][s]
    const int bb = (bm*128) >> 11;
#pragma unroll
    for (int n = 0; n < 4; ++n) {
      int cv = c0 + n*16 + row_l - 2048;
      int hh = cv >> 6, dd = cv & 63;
      float bvs = bias[c0 + n*16 + row_l];
      short* vrow = vt + ((size_t)((bb*16 + hh)*64 + dd))*SEQ;
#pragma unroll
      for (int m = 0; m < 4; ++m) {
        int s0 = (r0 + m*16 + kg*4) & (SEQ-1);
        bf16x4 o;
        o[0]=f2b(acc[m][n][0]+bvs); o[1]=f2b(acc[m][n][1]+bvs);
        o[2]=f2b(acc[m][n][2]+bvs); o[3]=f2b(acc[m][n][3]+bvs);
        *(bf16x4*)&vrow[s0] = o;
      }
    }
  } else {
    // MODE 0 (unused): swapped fp32 vector epilogue
#pragma unroll
    for (int m = 0; m < 4; ++m) {
      int row = r0 + m*16 + row_l;
#pragma unroll
      for (int n = 0; n < 4; ++n) {
        int colb = c0 + n*16 + kg*4;
        f32x4 o = acc[m][n] + *(const f32x4*)&bias[colb];
        *(f32x4*)&((float*)C)[(size_t)row*N + colb] = o;
      }
    }
  }
}

// ---- gemm2 variant: 64x128 tile, fp32 out, SWAPPED operands ----
// lane holds row = r0+m*16+row_l, cols c0+n*16+kg*4..+3 -> 8 float4 stores.
__global__ __launch_bounds__(256) void gemm_bt_small(const short* __restrict__ A,
                                                     const short* __restrict__ B,
                                                     const float* __restrict__ bias,
                                                     float* __restrict__ C,
                                                     int M, int N, int K) {
  __shared__ __align__(16) short As[64*64];
  __shared__ __align__(16) short Bs[128*64];
  const int t = threadIdx.x, l = t & 63, w = t >> 6;
  const int wr = w >> 1, wc = w & 1;
  const int lin = blockIdx.x + (blockIdx.y << 6);
  const int nwg = gridDim.x * gridDim.y;
  const int virt = (lin & 7) * (nwg >> 3) + (lin >> 3);
  const int bm = virt & 63, bn = virt >> 6;
  const int row_l = l & 15, kg = l >> 4;
  f32x4 acc[2][4];
  {
    f32x4 z = {0.f, 0.f, 0.f, 0.f};
#pragma unroll
    for (int m = 0; m < 2; ++m)
#pragma unroll
      for (int n = 0; n < 4; ++n) acc[m][n] = z;
  }
  for (int k0 = 0; k0 < K; k0 += 64) {
#pragma unroll
    for (int i = 0; i < 2; ++i) {
      int idx = i * 256 + t;
      int row = idx >> 3, cb = (idx & 7) * 8;
      gload16(A + (size_t)(bm*64 + row)*K + k0 + cb, &As[idx*8]);
    }
#pragma unroll
    for (int i = 0; i < 4; ++i) {
      int idx = i * 256 + t;
      int row = idx >> 3, cb = (idx & 7) * 8;
      gload16(B + (size_t)(bn*128 + row)*K + k0 + cb, &Bs[idx*8]);
    }
    __syncthreads();
#pragma unroll
    for (int ks = 0; ks < 2; ++ks) {
      bf16x8 af[2], bfv[4];
#pragma unroll
      for (int m = 0; m < 2; ++m)
        af[m] = *(const bf16x8*)&As[(wr*32 + m*16 + row_l)*64 + ks*32 + kg*8];
#pragma unroll
      for (int n = 0; n < 4; ++n)
        bfv[n] = *(const bf16x8*)&Bs[(wc*64 + n*16 + row_l)*64 + ks*32 + kg*8];
#pragma unroll
      for (int m = 0; m < 2; ++m)
#pragma unroll
        for (int n = 0; n < 4; ++n)
          acc[m][n] = __builtin_amdgcn_mfma_f32_16x16x32_bf16(bfv[n], af[m], acc[m][n], 0, 0, 0);
    }
    __syncthreads();
  }
  const int r0 = bm*64 + wr*32, c0 = bn*128 + wc*64;
#pragma unroll
  for (int m = 0; m < 2; ++m) {
    int row = r0 + m*16 + row_l;
#pragma unroll
    for (int n = 0; n < 4; ++n) {
      int colb = c0 + n*16 + kg*4;
      f32x4 o = acc[m][n] + *(const f32x4*)&bias[colb];
      *(f32x4*)&C[(size_t)row*N + colb] = o;
    }
  }
}

// ---------------- fused attention (128 q-rows / block, 8 waves) ----------------
// r12 structure (best known): LDS-staged K/V, dbuf, depth-2 register prefetch,
// lgkm-only barrier, g()-permuted K rows, in-register P via cvt_pk, setprio.

__global__ __launch_bounds__(512) void attn_fused(const short* __restrict__ qk,
                                                  const short* __restrict__ vtg,
                                                  float* __restrict__ attn_out,
                                                  short* __restrict__ ctx) {
  __shared__ __align__(16) short Ks[2][64*64];
  __shared__ __align__(16) short Vt[2][64*64];
  const int t = threadIdx.x, l = t & 63, w = t >> 6;
  const int row_l = l & 15, kg = l >> 4;
  const int rsl = row_l & 7;
  const int blk = blockIdx.x;
  const int bh = blk >> 4, q0 = (blk & 15) * 128;
  const int b = bh >> 4, h = bh & 15;
  const short* Qp = qk + (size_t)b*SEQ*2048 + h*64;
  const short* Kp = qk + (size_t)b*SEQ*2048 + 1024 + h*64;
  const short* Vg = vtg + (size_t)bh*64*SEQ;
  float* attn_bh = attn_out + (size_t)bh*SEQ*SEQ;
  const int qw = q0 + w*16;

  const bf16x8 aq0 = *(const bf16x8*)(Qp + (size_t)(qw + row_l)*2048 + kg*8);
  const bf16x8 aq1 = *(const bf16x8*)(Qp + (size_t)(qw + row_l)*2048 + 32 + kg*8);

  // staging: 512 threads cover the full 64x64 tile (1 slot each)
  const int a0 = t >> 3;                 // 0..63
  const int c8 = (t & 7) * 8;
  const int g0 = (a0 & 0x23) | ((a0 & 0x0C) << 1) | ((a0 & 0x10) >> 2);
  const int wof0 = a0*64 + (c8 ^ ((a0 & 7) << 3));

  // ---- pass 1: rsum; K dbuf + depth-2 reg prefetch, 1 lds_barrier/tile ----
  float rsum = 0.f;
  bf16x8 rkA, rkB;
  {
    bf16x8 r0 = *(const bf16x8*)(Kp + (size_t)g0*2048 + c8);
    *(bf16x8*)&Ks[0][wof0] = r0;
    rkA = *(const bf16x8*)(Kp + (size_t)(64 + g0)*2048 + c8);   // tile 1
  }
  lds_barrier();
#pragma unroll 2
  for (int kt = 0; kt < 32; ++kt) {
    const int cur = kt & 1;
    if (kt < 30) {
      const short* kb = Kp + (size_t)(kt + 2)*64*2048;
      rkB = *(const bf16x8*)(kb + (size_t)g0*2048 + c8);
    }
    __builtin_amdgcn_s_setprio(1);
#pragma unroll
    for (int nt = 0; nt < 4; ++nt) {
      const int row = nt*16 + row_l;
      bf16x8 k0 = *(const bf16x8*)&Ks[cur][row*64 + ((kg ^ rsl) << 3)];
      bf16x8 k1 = *(const bf16x8*)&Ks[cur][row*64 + (((kg|4) ^ rsl) << 3)];
      f32x4 s = {0.f, 0.f, 0.f, 0.f};
      s = __builtin_amdgcn_mfma_f32_16x16x32_bf16(k0, aq0, s, 0, 0, 0);
      s = __builtin_amdgcn_mfma_f32_16x16x32_bf16(k1, aq1, s, 0, 0, 0);
      rsum += (nexp2(s[0]) + nexp2(s[1])) + (nexp2(s[2]) + nexp2(s[3]));
    }
    __builtin_amdgcn_s_setprio(0);
    if (kt < 31) {
      *(bf16x8*)&Ks[cur^1][wof0] = rkA;   // waits only rkA's load; rkB stays in flight
    }
    lds_barrier();
    rkA = rkB;
  }
  rsum += __shfl_xor(rsum, 16);
  rsum += __shfl_xor(rsum, 32);
  const float inv = 1.f / rsum;

  f32x4 actx[4];
  {
    f32x4 z = {0.f, 0.f, 0.f, 0.f};
#pragma unroll
    for (int e = 0; e < 4; ++e) actx[e] = z;
  }

  // ---- pass 2: recompute, write attn, PV; K+V dbuf + depth-2 prefetch ----
  bf16x8 rvA, rvB;
  {
    bf16x8 k0 = *(const bf16x8*)(Kp + (size_t)g0*2048 + c8);
    bf16x8 v0 = *(const bf16x8*)(Vg + (size_t)a0*SEQ + c8);
    *(bf16x8*)&Ks[0][wof0] = k0;
    *(bf16x8*)&Vt[0][wof0] = v0;
    rkA = *(const bf16x8*)(Kp + (size_t)(64 + g0)*2048 + c8);
    rvA = *(const bf16x8*)(Vg + (size_t)(64 + a0*SEQ) + c8);
  }
  lds_barrier();
#pragma unroll 2
  for (int kt = 0; kt < 32; ++kt) {
    const int cur = kt & 1;
    if (kt < 30) {
      const short* kb = Kp + (size_t)(kt + 2)*64*2048;
      const short* vb = Vg + (kt + 2)*64;
      rkB = *(const bf16x8*)(kb + (size_t)g0*2048 + c8);
      rvB = *(const bf16x8*)(vb + (size_t)a0*SEQ + c8);
    }
    f32x4 pf[4];
    __builtin_amdgcn_s_setprio(1);
#pragma unroll
    for (int nt = 0; nt < 4; ++nt) {
      const int row = nt*16 + row_l;
      bf16x8 k0 = *(const bf16x8*)&Ks[cur][row*64 + ((kg ^ rsl) << 3)];
      bf16x8 k1 = *(const bf16x8*)&Ks[cur][row*64 + (((kg|4) ^ rsl) << 3)];
      f32x4 s = {0.f, 0.f, 0.f, 0.f};
      s = __builtin_amdgcn_mfma_f32_16x16x32_bf16(k0, aq0, s, 0, 0, 0);
      s = __builtin_amdgcn_mfma_f32_16x16x32_bf16(k1, aq1, s, 0, 0, 0);
      f32x4 p;
      p[0] = nexp2(s[0]) * inv; p[1] = nexp2(s[1]) * inv;
      p[2] = nexp2(s[2]) * inv; p[3] = nexp2(s[3]) * inv;
      *(f32x4*)&attn_bh[(size_t)(qw + row_l)*SEQ + kt*64 + (nt&2)*16 + kg*8 + (nt&1)*4] = p;
      pf[nt] = p;
    }
#pragma unroll
    for (int hh = 0; hh < 2; ++hh) {
      u32x4 pq;
      pq[0] = cvtpk(pf[2*hh][0],   pf[2*hh][1]);
      pq[1] = cvtpk(pf[2*hh][2],   pf[2*hh][3]);
      pq[2] = cvtpk(pf[2*hh+1][0], pf[2*hh+1][1]);
      pq[3] = cvtpk(pf[2*hh+1][2], pf[2*hh+1][3]);
      bf16x8 pb = *(bf16x8*)&pq;
      const int vslot = ((kg | (hh << 2)) ^ rsl) << 3;
#pragma unroll
      for (int e = 0; e < 4; ++e) {
        bf16x8 va = *(const bf16x8*)&Vt[cur][(e*16 + row_l)*64 + vslot];
        actx[e] = __builtin_amdgcn_mfma_f32_16x16x32_bf16(va, pb, actx[e], 0, 0, 0);
      }
    }
    __builtin_amdgcn_s_setprio(0);
    if (kt < 31) {
      *(bf16x8*)&Ks[cur^1][wof0] = rkA;
      *(bf16x8*)&Vt[cur^1][wof0] = rvA;
    }
    lds_barrier();
    rkA = rkB;
    rvA = rvB;
  }
  // ctx epilogue
#pragma unroll
  for (int e = 0; e < 4; ++e) {
    int2 o;
    o.x = (int)cvtpk(actx[e][0], actx[e][1]);
    o.y = (int)cvtpk(actx[e][2], actx[e][3]);
    *(int2*)&ctx[(size_t)(b*SEQ + qw + row_l)*DM + h*64 + e*16 + kg*4] = o;
  }
}

// ---------------- launch ----------------

extern "C" void kernel_launch(void* const* d_in, const int* in_sizes, int n_in,
                              void* d_out, int out_size, void* d_ws, size_t ws_size,
                              hipStream_t stream) {
  const float* x    = (const float*)d_in[0];
  const float* Wq   = (const float*)d_in[1];
  const float* bq   = (const float*)d_in[2];
  const float* Wk   = (const float*)d_in[3];
  const float* bk   = (const float*)d_in[4];
  const float* Wv   = (const float*)d_in[5];
  const float* bv   = (const float*)d_in[6];
  const float* Wo   = (const float*)d_in[7];
  const float* bo   = (const float*)d_in[8];
  const float* gate = (const float*)d_in[9];
  const float* ent  = (const float*)d_in[10];

  char* ws = (char*)d_ws;
  short* xb   = (short*)(ws);                          // 4096x1024 bf16 (8 MB); reused as ctx
  short* Wcat = (short*)(ws + ((size_t)8  << 20));     // 3072x1024 bf16 (6 MB)
  short* Wob  = (short*)(ws + ((size_t)14 << 20));     // 1024x1024 bf16 (2 MB)
  float* bcat = (float*)(ws + ((size_t)16 << 20));     // 3072 f32
  short* qkb  = (short*)(ws + ((size_t)17 << 20));     // 4096x2048 bf16 (16 MB)
  short* vtg  = (short*)(ws + ((size_t)33 << 20));     // 32x64x2048 bf16 (16 MB)
  short* ctxb = xb;                                    // reuse (x consumed by gemm1)

  float* outp  = (float*)d_out;
  float* attnp = outp + (size_t)MROWS * DM;

  k_prep<<<3660, 256, 0, stream>>>(x, Wq, Wk, Wv, Wo, bq, bk, bv, gate, ent,
                                   xb, Wcat, Wob, bcat);
  gemm_bt<1, 5><<<dim3(32, 24), 256, 0, stream>>>(xb, Wcat, bcat, qkb, vtg, MROWS, 3072, DM);
  attn_fused<<<512, 512, 0, stream>>>(qkb, vtg, attnp, ctxb);
  gemm_bt_small<<<dim3(64, 8), 256, 0, stream>>>(ctxb, Wob, bo, outp, MROWS, DM, DM);
}